// Round 2
// baseline (273.527 us; speedup 1.0000x reference)
//
#include <hip/hip_runtime.h>
#include <cstdint>

// B=4, L=2048, H=512, HEADS=8, D=64.
// Only the DIAGONAL of softmax(scores) is consumed:
//   diag_i = exp(s_ii) / sum_j exp(s_ij),
//   s_ij = q_i.k_j + q_i.Wp[1983+j-i...] + Wp_b[l-1+j-i]
// Logits in log2 units (q pre-scaled by log2e/8 via prep-scaled Wq, bias by log2e).

typedef unsigned short u16;
typedef __bf16 bf16x8 __attribute__((ext_vector_type(8)));
typedef __bf16 bf16x2 __attribute__((ext_vector_type(2)));
typedef float  f32x16 __attribute__((ext_vector_type(16)));
typedef uint32_t __attribute__((address_space(1))) as1_u32;
typedef uint32_t __attribute__((address_space(3))) as3_u32;

__device__ __forceinline__ u16 f2bf(float f) {
  __bf16 h = (__bf16)f;
  return __builtin_bit_cast(u16, h);
}
__device__ __forceinline__ uint32_t pkbf(float a, float b) {
  bf16x2 v; v[0] = (__bf16)a; v[1] = (__bf16)b;
  return __builtin_bit_cast(uint32_t, v);
}
__device__ __forceinline__ float bf2f(u16 u) {
  return __uint_as_float(((uint32_t)u) << 16);
}
__device__ __forceinline__ float exp2v(float x) {
  float r;
  asm("v_exp_f32 %0, %1" : "=v"(r) : "v"(x));
  return r;
}
__device__ __forceinline__ void gl_lds16(const void* g, void* l) {
  __builtin_amdgcn_global_load_lds((const as1_u32*)g, (as3_u32*)l, 16, 0, 0);
}

// ---------------------------------------------------------------------------
// Prep: fp32 -> bf16 for q_in/k_in/v_in, Wq/Wk/Wv/Wo, Wp (padded to 4096 rows)
// Wq is pre-scaled by log2e/8 so the QKV epilogue needs no multiply.
// ---------------------------------------------------------------------------
__global__ __launch_bounds__(256) void prep_kernel(
    const float* __restrict__ qin, const float* __restrict__ kin, const float* __restrict__ vin,
    const float* __restrict__ wq,  const float* __restrict__ wk,  const float* __restrict__ wv,
    const float* __restrict__ wo,  const float* __restrict__ wp,
    u16* __restrict__ xq, u16* __restrict__ xk, u16* __restrict__ xv,
    u16* __restrict__ bwq, u16* __restrict__ bwk, u16* __restrict__ bwv,
    u16* __restrict__ bwo, u16* __restrict__ bwp) {
  long u = (long)blockIdx.x * 256 + threadIdx.x;
  const float* src; u16* dst; long off; float qs = 1.0f;
  if      (u < 524288L)  { src = qin; dst = xq;  off = u; }
  else if (u < 1048576L) { src = kin; dst = xk;  off = u - 524288L; }
  else if (u < 1572864L) { src = vin; dst = xv;  off = u - 1048576L; }
  else if (u < 1605632L) { src = wq;  dst = bwq; off = u - 1572864L; qs = 0.18033688f; }
  else if (u < 1638400L) { src = wk;  dst = bwk; off = u - 1605632L; }
  else if (u < 1671168L) { src = wv;  dst = bwv; off = u - 1638400L; }
  else if (u < 1703936L) { src = wo;  dst = bwo; off = u - 1671168L; }
  else if (u < 1736696L) { src = wp;  dst = bwp; off = u - 1703936L; }
  else {  // zero-fill Wp pad row 4095
    long o = (u - 1736696L) * 8 + 262080L;
    uint4 z = {0u, 0u, 0u, 0u};
    *(uint4*)(bwp + o) = z;
    return;
  }
  const float4* s4 = (const float4*)(src + off * 8);
  float4 a = s4[0], b = s4[1];
  uint32_t p0 = pkbf(a.x * qs, a.y * qs);
  uint32_t p1 = pkbf(a.z * qs, a.w * qs);
  uint32_t p2 = pkbf(b.x * qs, b.y * qs);
  uint32_t p3 = pkbf(b.z * qs, b.w * qs);
  uint4 o = {p0, p1, p2, p3};
  *(uint4*)(dst + off * 8) = o;
}

// ---------------------------------------------------------------------------
// 64x64-tile GEMM core (C = A @ W^T), 4 waves, each wave one 32x32 quadrant.
// BK=32, 16 k-iters, global_load_lds staging, chunk-XOR swizzle (conflict-free
// verified by SQ_LDS_BANK_CONFLICT=0 on the 128-tile ancestor).
// ---------------------------------------------------------------------------
__device__ __forceinline__ void gemm64_core(
    const u16* __restrict__ A, const u16* __restrict__ W, int m0, int n0,
    u16* Al, u16* Bl, int tid, f32x16& acc) {
  const int lane = tid & 63, w = tid >> 6;
  const int wi = w >> 1, wj = w & 1;
  const int l31 = lane & 31, lh = lane >> 5;
  const int r = tid >> 2, ch = tid & 3;
  const int gch = ch ^ ((r >> 1) & 3);
  for (int kb = 0; kb < 16; ++kb) {
    gl_lds16(A + (long)(m0 + r) * 512 + kb * 32 + gch * 8, (char*)Al + w * 64 * 16);
    gl_lds16(W + (long)(n0 + r) * 512 + kb * 32 + gch * 8, (char*)Bl + w * 64 * 16);
    __syncthreads();
    bf16x8 af[2], bfr[2];
#pragma unroll
    for (int ks = 0; ks < 2; ++ks) {
      int c2 = 2 * ks + lh;
      int rA = 32 * wi + l31;
      int rB = 32 * wj + l31;
      af[ks]  = *(const bf16x8*)((char*)Al + (rA * 4 + (c2 ^ ((rA >> 1) & 3))) * 16);
      bfr[ks] = *(const bf16x8*)((char*)Bl + (rB * 4 + (c2 ^ ((rB >> 1) & 3))) * 16);
    }
#pragma unroll
    for (int ks = 0; ks < 2; ++ks)
      acc = __builtin_amdgcn_mfma_f32_32x32x16_bf16(af[ks], bfr[ks], acc, 0, 0, 0);
    __syncthreads();
  }
}

// gemm_bt: final projection, fp32 out row-major. 1024 blocks (8 XCD chunks of
// 16 m-tiles x 8 n-tiles each) -> ~4 blocks/CU instead of the old 1.
__global__ __launch_bounds__(256, 4) void gemm_bt(
    const u16* __restrict__ A, const u16* __restrict__ W, const float* __restrict__ bias,
    float* __restrict__ ofp) {
  __shared__ u16 Al[64 * 32];
  __shared__ u16 Bl[64 * 32];
  const int tid = threadIdx.x;
  const int lane = tid & 63, w = tid >> 6;
  const int wi = w >> 1, wj = w & 1;
  const int l31 = lane & 31, lh = lane >> 5;
  const int u = (blockIdx.x & 7) * 128 + (blockIdx.x >> 3);
  const int m0 = (u >> 3) * 64, n0 = (u & 7) * 64;

  float bv = bias[n0 + 32 * wj + l31];
  f32x16 acc;
#pragma unroll
  for (int rr = 0; rr < 16; ++rr) acc[rr] = bv;

  gemm64_core(A, W, m0, n0, Al, Bl, tid, acc);

  int n = n0 + 32 * wj + l31;
#pragma unroll
  for (int rr = 0; rr < 16; ++rr) {
    int row = m0 + 32 * wi + (rr & 3) + 8 * (rr >> 2) + 4 * lh;
    ofp[(long)row * 512 + n] = acc[rr];
  }
}

// qkv_gemm: 3072 blocks (3 mats x 1024), bf16 out in (b,h,l,d).
__global__ __launch_bounds__(256, 4) void qkv_gemm(
    const u16* __restrict__ xq, const u16* __restrict__ xk, const u16* __restrict__ xv,
    const u16* __restrict__ wqp, const u16* __restrict__ wkp, const u16* __restrict__ wvp,
    const float* __restrict__ bq, const float* __restrict__ bk, const float* __restrict__ bv,
    u16* __restrict__ oq, u16* __restrict__ ok, u16* __restrict__ ov) {
  __shared__ u16 Al[64 * 32];
  __shared__ u16 Bl[64 * 32];
  const int mat = blockIdx.x >> 10;
  const int t = blockIdx.x & 1023;
  const u16* A = (mat == 0) ? xq : (mat == 1) ? xk : xv;
  const u16* W = (mat == 0) ? wqp : (mat == 1) ? wkp : wvp;
  const float* bias = (mat == 0) ? bq : (mat == 1) ? bk : bv;
  u16* obf = (mat == 0) ? oq : (mat == 1) ? ok : ov;
  const float bsc = (mat == 0) ? 0.18033688f : 1.0f;

  const int tid = threadIdx.x;
  const int lane = tid & 63, w = tid >> 6;
  const int wi = w >> 1, wj = w & 1;
  const int l31 = lane & 31, lh = lane >> 5;
  const int u = (t & 7) * 128 + (t >> 3);
  const int m0 = (u >> 3) * 64, n0 = (u & 7) * 64;

  float bvv = bias[n0 + 32 * wj + l31] * bsc;
  f32x16 acc;
#pragma unroll
  for (int rr = 0; rr < 16; ++rr) acc[rr] = bvv;

  gemm64_core(A, W, m0, n0, Al, Bl, tid, acc);

  int n = n0 + 32 * wj + l31;
  int h = n >> 6, d = n & 63;
#pragma unroll
  for (int rr = 0; rr < 16; ++rr) {
    int row = m0 + 32 * wi + (rr & 3) + 8 * (rr >> 2) + 4 * lh;
    int b = row >> 11, l = row & 2047;
    obf[(((long)(b * 8 + h)) * 2048 + l) * 64 + d] = f2bf(acc[rr]);
  }
}

// ---------------------------------------------------------------------------
// Attention. One block per (b,h, 64-row i-tile); 4 waves; launch_bounds(256,3)
// (VGPR cap 170) so kf[4]/bw[4] live as in-flight arrays — the round-1 build
// chose 52 VGPRs and serialized every load-use chain (the 60% stall).
// Pipeline per iteration jt:
//   kf[4]   <- K tile jt           (global loads, issued early)
//   bvn     <- Wp_b for g=jt+3     (bias prefetch, used next iter)
//   pblock(jt+2): bw[4] preloaded -> 4 MFMA -> pack -> ds_write ring
//   barrier
//   pn[16]  <- P for iter jt+1     (slots jt+1, jt+2 valid; latency hides
//                                   under this iter's MFMA+exp2)
//   accS = unpack(pc); 4 MFMA with kf; v_exp_f32 x16; rsum; pc = pn
// Ring hazard (1 barrier/iter, 4 slots): pn reads (post-bar jt) touch slots
// (jt+1)&3,(jt+2)&3; concurrent writes (pre-bar jt+1) touch (jt+3)&3 — disjoint.
// ---------------------------------------------------------------------------
__global__ __launch_bounds__(256, 3) void attn_kernel(
    const u16* __restrict__ qw, const u16* __restrict__ kw, const u16* __restrict__ vw,
    const u16* __restrict__ wpw, const float* __restrict__ wpb, u16* __restrict__ outp) {
  __shared__ u16 Pl[283 * 66];     // 256-row ring + 27 mirror rows, stride 66
  __shared__ float sdiag[64];
  __shared__ float rssum[128];
  __shared__ float attw[64];

  const int tid = threadIdx.x, lane = tid & 63, w = tid >> 6;
  const int wi = w >> 1, wj = w & 1;
  const int sbi = blockIdx.x;
  const int kk_ = sbi >> 3;
  const int bh = (sbi & 7) + 8 * (kk_ >> 5);   // XCD swizzle: 32 i-tiles/bh per XCD
  const int it = kk_ & 31;
  const int i0 = it * 64, base = 1984 - i0;
  const u16* qb = qw + (long)bh * 2048 * 64;
  const u16* kb = kw + (long)bh * 2048 * 64;
  const u16* vb = vw + (long)bh * 2048 * 64;

  const int l31 = lane & 31, lh = lane >> 5;
  const int iibase = 32 * wi + 4 * lh;

  bf16x8 aq[4];
  {
    int row = i0 + 32 * wi + l31;
    const u16* p = qb + (long)row * 64 + lh * 8;
#pragma unroll
    for (int kk = 0; kk < 4; ++kk) aq[kk] = *(const bf16x8*)(p + kk * 16);
  }

  float rsum[16];
#pragma unroll
  for (int r = 0; r < 16; ++r) rsum[r] = 0.f;

  const int browc = base + 32 * wj + l31;

  auto ldbias = [&](int g) -> float {
    int brow = browc + 64 * g;
    int bidx = brow > 4094 ? 4094 : brow;
    return wpb[bidx] * 1.44269504f;
  };

  auto pblock = [&](int g, float bv) {
    const u16* bp = wpw + (long)(browc + 64 * g) * 64 + lh * 8;
    bf16x8 bw[4];
#pragma unroll
    for (int kk = 0; kk < 4; ++kk) bw[kk] = *(const bf16x8*)(bp + kk * 16);
    f32x16 accP;
#pragma unroll
    for (int r = 0; r < 16; ++r) accP[r] = bv;
#pragma unroll
    for (int kk = 0; kk < 4; ++kk)
      accP = __builtin_amdgcn_mfma_f32_32x32x16_bf16(aq[kk], bw[kk], accP, 0, 0, 0);
    int colp = (g & 3) * 64 + 32 * wj + l31;
    uint32_t pk0[8];
#pragma unroll
    for (int m = 0; m < 4; ++m) {
      pk0[2 * m]     = pkbf(accP[4 * m + 0], accP[4 * m + 1]);
      pk0[2 * m + 1] = pkbf(accP[4 * m + 2], accP[4 * m + 3]);
    }
    u16* wl = &Pl[colp * 66 + iibase];
#pragma unroll
    for (int m = 0; m < 4; ++m) {
      *(uint32_t*)(wl + 8 * m) = pk0[2 * m];
      *(uint32_t*)(wl + 8 * m + 2) = pk0[2 * m + 1];
    }
    if (((g & 3) == 0) && (wj == 0) && (l31 < 27)) {  // mirror rows 0..26
      u16* wl2 = wl + 256 * 66;
#pragma unroll
      for (int m = 0; m < 4; ++m) {
        *(uint32_t*)(wl2 + 8 * m) = pk0[2 * m];
        *(uint32_t*)(wl2 + 8 * m + 2) = pk0[2 * m + 1];
      }
    }
  };

  pblock(0, ldbias(0));
  pblock(1, ldbias(1));
  float bvc = ldbias(2);
  __syncthreads();

  const int W1c = 63 + 32 * wj + l31 - iibase;
  uint32_t pc[16];
  {
    int b_ = ((W1c - 27) & 255) + 27;
    const u16* rb = &Pl[b_ * 66 + iibase - 27 * 65];
#pragma unroll
    for (int r = 0; r < 16; ++r) {
      const int lrr = (r & 3) + 8 * (r >> 2);
      pc[r] = rb[(27 - lrr) * 65];
    }
  }

  for (int jt = 0; jt < 32; ++jt) {
    bf16x8 kf[4];
    {
      const u16* bp = kb + (long)(jt * 64 + 32 * wj + l31) * 64 + lh * 8;
#pragma unroll
      for (int kk = 0; kk < 4; ++kk) kf[kk] = *(const bf16x8*)(bp + kk * 16);
    }
    float bvn = (jt <= 29) ? ldbias(jt + 3) : 0.f;
    if (jt <= 30) pblock(jt + 2, bvc);
    __syncthreads();                 // the ONLY barrier per iteration

    uint32_t pn[16];
    if (jt <= 30) {
      int W1 = 64 * (jt + 1) + W1c;
      int b_ = ((W1 - 27) & 255) + 27;
      const u16* rb = &Pl[b_ * 66 + iibase - 27 * 65];
#pragma unroll
      for (int r = 0; r < 16; ++r) {
        const int lrr = (r & 3) + 8 * (r >> 2);
        pn[r] = rb[(27 - lrr) * 65];
      }
    }

    f32x16 accS;
#pragma unroll
    for (int r = 0; r < 16; ++r) accS[r] = __uint_as_float(pc[r] << 16);
#pragma unroll
    for (int kk = 0; kk < 4; ++kk)
      accS = __builtin_amdgcn_mfma_f32_32x32x16_bf16(aq[kk], kf[kk], accS, 0, 0, 0);
#pragma unroll
    for (int r = 0; r < 16; ++r) rsum[r] += exp2v(accS[r]);

    if ((jt == it) && (wi == wj)) {  // wave-uniform branch
#pragma unroll
      for (int r = 0; r < 16; ++r) {
        const int lrr = (r & 3) + 8 * (r >> 2);
        if ((lrr + 4 * lh) == l31) sdiag[32 * wi + l31] = accS[r];
      }
    }
#pragma unroll
    for (int r = 0; r < 16; ++r) pc[r] = pn[r];
    bvc = bvn;
  }

  // reduce row partials across the 32 lanes sharing each row
#pragma unroll
  for (int r = 0; r < 16; ++r) {
    float v = rsum[r];
    v += __shfl_xor(v, 1);
    v += __shfl_xor(v, 2);
    v += __shfl_xor(v, 4);
    v += __shfl_xor(v, 8);
    v += __shfl_xor(v, 16);
    rsum[r] = v;
  }
  if (l31 == 0) {
#pragma unroll
    for (int r = 0; r < 16; ++r) {
      int lr = (r & 3) + 8 * (r >> 2) + 4 * lh;
      rssum[(32 * wi + lr) * 2 + wj] = rsum[r];
    }
  }
  __syncthreads();
  if (tid < 64) {
    float S = rssum[2 * tid] + rssum[2 * tid + 1];
    attw[tid] = exp2v(sdiag[tid]) / S;
  }
  __syncthreads();
  // out_pre[b*2048 + i][h*64 + d] = diag * v   (bf16)
  {
    int r = tid >> 2, dd = (tid & 3) * 16;
    float a = attw[r];
    int b = bh >> 3, h = bh & 7;
    const u16* vp = vb + (long)(i0 + r) * 64 + dd;
    u16* op = outp + ((long)(b * 2048 + i0 + r)) * 512 + h * 64 + dd;
    uint4 v0 = *(const uint4*)vp;
    uint4 v1 = *(const uint4*)(vp + 8);
    uint32_t vin[8] = {v0.x, v0.y, v0.z, v0.w, v1.x, v1.y, v1.z, v1.w};
    uint32_t vout[8];
#pragma unroll
    for (int e = 0; e < 8; ++e) {
      float lo = bf2f((u16)(vin[e] & 0xffffu)) * a;
      float hi = bf2f((u16)(vin[e] >> 16)) * a;
      vout[e] = pkbf(lo, hi);
    }
    uint4 o0 = {vout[0], vout[1], vout[2], vout[3]};
    uint4 o1 = {vout[4], vout[5], vout[6], vout[7]};
    *(uint4*)op = o0;
    *(uint4*)(op + 8) = o1;
  }
}

// ---------------------------------------------------------------------------
extern "C" void kernel_launch(void* const* d_in, const int* in_sizes, int n_in,
                              void* d_out, int out_size, void* d_ws, size_t ws_size,
                              hipStream_t stream) {
  (void)in_sizes; (void)n_in; (void)out_size; (void)ws_size;
  const float* q_in = (const float*)d_in[0];
  const float* k_in = (const float*)d_in[1];
  const float* v_in = (const float*)d_in[2];
  const float* Wq_w = (const float*)d_in[3];
  const float* Wq_b = (const float*)d_in[4];
  const float* Wk_w = (const float*)d_in[5];
  const float* Wk_b = (const float*)d_in[6];
  const float* Wv_w = (const float*)d_in[7];
  const float* Wv_b = (const float*)d_in[8];
  const float* Wo_w = (const float*)d_in[9];
  const float* Wo_b = (const float*)d_in[10];
  const float* Wp_w = (const float*)d_in[11];
  const float* Wp_b = (const float*)d_in[12];

  char* ws = (char*)d_ws;
  u16* xq   = (u16*)(ws + 0);         // 8 MB  bf16 q_in
  u16* xk   = (u16*)(ws + 8388608);   // 8 MB
  u16* xv   = (u16*)(ws + 16777216);  // 8 MB
  u16* wq   = (u16*)(ws + 25165824);  // 512 KB each
  u16* wk   = (u16*)(ws + 25690112);
  u16* wv   = (u16*)(ws + 26214400);
  u16* wo   = (u16*)(ws + 26738688);
  u16* wp   = (u16*)(ws + 27262976);  // 4096x64 bf16 (row 4095 zero)
  u16* q_ws = (u16*)(ws + 27787264);  // (b,h,l,d) bf16, pre-scaled log2e/8
  u16* k_ws = (u16*)(ws + 36175872);
  u16* v_ws = (u16*)(ws + 44564480);
  u16* opre = (u16*)(ws + 52953088);  // (b*l, h*d) bf16 diag-scaled v

  prep_kernel<<<6784, 256, 0, stream>>>(q_in, k_in, v_in, Wq_w, Wk_w, Wv_w, Wo_w, Wp_w,
                                        xq, xk, xv, wq, wk, wv, wo, wp);
  qkv_gemm<<<3072, 256, 0, stream>>>(xq, xk, xv, wq, wk, wv, Wq_b, Wk_b, Wv_b,
                                     q_ws, k_ws, v_ws);
  attn_kernel<<<1024, 256, 0, stream>>>(q_ws, k_ws, v_ws, wp, Wp_b, opre);
  gemm_bt<<<1024, 256, 0, stream>>>(opre, wo, Wo_b, (float*)d_out);
}